// Round 5
// baseline (10716.862 us; speedup 1.0000x reference)
//
#include <hip/hip_runtime.h>
#include <cmath>

#define WIDTH 384
#define HW 147456        // 384*384
#define CHW 4718592      // 32*384*384
#define NCH 32
#define NV 2048

// ---------------------------------------------------------------------------
// numpy pairwise_sum replica, f32, contraction-proof.
// SQ=0: sum a[i]; SQ=1: sum (a[i]-mu)^2 (separate f32 sub, mul, add — like np).
// ---------------------------------------------------------------------------
template <int SQ>
__device__ float np_pw(const float* a, int n, float mu) {
  if (n < 8) {
    float res = 0.0f;
    for (int i = 0; i < n; i++) {
      float v = a[i];
      if (SQ) { float d = __fsub_rn(v, mu); v = __fmul_rn(d, d); }
      res = __fadd_rn(res, v);
    }
    return res;
  }
  if (n <= 128) {
    float r[8];
#pragma unroll
    for (int j = 0; j < 8; j++) {
      float v = a[j];
      if (SQ) { float d = __fsub_rn(v, mu); v = __fmul_rn(d, d); }
      r[j] = v;
    }
    int i;
    for (i = 8; i + 8 <= n; i += 8) {
#pragma unroll
      for (int j = 0; j < 8; j++) {
        float v = a[i + j];
        if (SQ) { float d = __fsub_rn(v, mu); v = __fmul_rn(d, d); }
        r[j] = __fadd_rn(r[j], v);
      }
    }
    float res = __fadd_rn(__fadd_rn(__fadd_rn(r[0], r[1]), __fadd_rn(r[2], r[3])),
                          __fadd_rn(__fadd_rn(r[4], r[5]), __fadd_rn(r[6], r[7])));
    for (; i < n; i++) {
      float v = a[i];
      if (SQ) { float d = __fsub_rn(v, mu); v = __fmul_rn(d, d); }
      res = __fadd_rn(res, v);
    }
    return res;
  }
  int n2 = n / 2; n2 -= n2 % 8;
  return __fadd_rn(np_pw<SQ>(a, n2, mu), np_pw<SQ>(a + n2, n - n2, mu));
}

// ---------------------------------------------------------------------------
// prep: ee[v] = (emb[v]*emb[v]).sum() exactly as numpy pairwise (n=32 path):
// 8 accumulators seeded, one unrolled pass (i=8,16,24), nested-pair combine.
// ---------------------------------------------------------------------------
__global__ __launch_bounds__(256) void prep_kernel(
    const float* __restrict__ emb, float* __restrict__ ee) {
  int v = blockIdx.x * 256 + threadIdx.x;
  if (v >= NV) return;
  const float* e = emb + v * 32;
  float r[8];
#pragma unroll
  for (int j = 0; j < 8; j++) r[j] = __fmul_rn(e[j], e[j]);
#pragma unroll
  for (int i = 8; i < 32; i += 8)
#pragma unroll
    for (int j = 0; j < 8; j++) r[j] = __fadd_rn(r[j], __fmul_rn(e[i + j], e[i + j]));
  ee[v] = __fadd_rn(__fadd_rn(__fadd_rn(r[0], r[1]), __fadd_rn(r[2], r[3])),
                    __fadd_rn(__fadd_rn(r[4], r[5]), __fadd_rn(r[6], r[7])));
}

// ---------------------------------------------------------------------------
// unfold: P[n][c][py][px] = x - acc   (f32 subtract, patch-major)
// ---------------------------------------------------------------------------
__global__ __launch_bounds__(256) void unfold_kernel(
    const float* __restrict__ x, const float* __restrict__ acc,
    float* __restrict__ P, int p, int nw) {
  int t = blockIdx.x * 256 + threadIdx.x;   // grid exact: CHW
  int px = t % p;  int t1 = t / p;
  int py = t1 % p; int t2 = t1 / p;
  int c  = t2 % NCH;
  int n  = t2 / NCH;
  int i = n / nw, j = n % nw;
  size_t img = (size_t)c * HW + (size_t)(i * p + py) * WIDTH + (j * p + px);
  P[t] = __fsub_rn(x[img], acc[img]);
}

// ---------------------------------------------------------------------------
// conv3x3, per-patch SAME zero pad, patch-major, f32 sequential FMA in
// k-order (ci,ky,kx) — im2col+sgemm semantics (zero-pad taps are exact
// identities under fmaf, so skipping preserves the chain).
// OUT_ACC: fold + acc_img += zq*0.5 + (conv+b)*0.5
// ---------------------------------------------------------------------------
template <int OUT_ACC>
__global__ __launch_bounds__(256) void convp_kernel(
    const float* __restrict__ in, float* __restrict__ outb,
    const float* __restrict__ zqb, float* __restrict__ acc,
    const float* __restrict__ wsrc, const float* __restrict__ bias, int p, int nw) {
  int t = blockIdx.x * 256 + threadIdx.x;   // grid exact: CHW
  int px = t % p;  int t1 = t / p;
  int py = t1 % p; int t2 = t1 / p;
  int co = t2 % NCH;
  int n  = t2 / NCH;
  int pp = p * p;
  const float* pbase = in + (size_t)n * NCH * pp;
  const float* wbase = wsrc + co * 288;     // w[co][ci][ky][kx]

  float a = 0.0f;
  for (int ci = 0; ci < NCH; ci++) {
    const float* pc = pbase + ci * pp;
    const float* wc = wbase + ci * 9;
#pragma unroll
    for (int dy = 0; dy < 3; dy++) {
      int iy = py + dy - 1;
      if ((unsigned)iy >= (unsigned)p) continue;
#pragma unroll
      for (int dx = 0; dx < 3; dx++) {
        int ix = px + dx - 1;
        if ((unsigned)ix >= (unsigned)p) continue;
        a = fmaf(pc[iy * p + ix], wc[dy * 3 + dx], a);
      }
    }
  }
  float r = __fadd_rn(a, bias[co]);
  if (OUT_ACC) {
    int i = n / nw, j = n % nw;
    size_t img = (size_t)co * HW + (size_t)(i * p + py) * WIDTH + (j * p + px);
    float dec = __fadd_rn(__fmul_rn(zqb[t], 0.5f), __fmul_rn(r, 0.5f));
    acc[img] = __fadd_rn(acc[img], dec);
  } else {
    outb[t] = r;
  }
}

// ---------------------------------------------------------------------------
// GroupNorm stats, numpy-exact: mean = pairwise_sum/ne (f32 div), var =
// pairwise_sum((x-mu)^2)/ne, rs = 1/sqrtf(var+1e-5f). 8 lanes per group,
// chunk boundaries == numpy recursion splits for ne in {1024,4096,9216,16384}.
// ---------------------------------------------------------------------------
__global__ __launch_bounds__(64) void gn_stats_kernel(
    const float* __restrict__ buf, float2* __restrict__ stats, int p) {
  __shared__ float lds[8][8];
  __shared__ float mus[8];
  int gi = threadIdx.x >> 3, l = threadIdx.x & 7;
  int grp = blockIdx.x * 8 + gi;            // grid exact: ngroups/8
  int pp = p * p, ne = 4 * pp, chunk = ne >> 3;
  const float* base = buf + ((size_t)(grp >> 3) * NCH + (size_t)(grp & 7) * 4) * pp;

  lds[gi][l] = np_pw<0>(base + l * chunk, chunk, 0.0f);
  __syncthreads();
  if (l == 0) {
    float* r = lds[gi];
    float s = __fadd_rn(__fadd_rn(__fadd_rn(r[0], r[1]), __fadd_rn(r[2], r[3])),
                        __fadd_rn(__fadd_rn(r[4], r[5]), __fadd_rn(r[6], r[7])));
    mus[gi] = __fdiv_rn(s, (float)ne);
  }
  __syncthreads();
  float mu = mus[gi];
  lds[gi][l] = np_pw<1>(base + l * chunk, chunk, mu);
  __syncthreads();
  if (l == 0) {
    float* r = lds[gi];
    float s2 = __fadd_rn(__fadd_rn(__fadd_rn(r[0], r[1]), __fadd_rn(r[2], r[3])),
                         __fadd_rn(__fadd_rn(r[4], r[5]), __fadd_rn(r[6], r[7])));
    float var = __fdiv_rn(s2, (float)ne);
    float rs = __fdiv_rn(1.0f, __fsqrt_rn(__fadd_rn(var, 1e-5f)));
    stats[grp] = make_float2(mu, rs);
  }
}

// ---------------------------------------------------------------------------
// GN affine + exact GELU, all f32 ops explicit; erf = f64 erf rounded to f32.
// ---------------------------------------------------------------------------
__global__ __launch_bounds__(256) void gn_gelu_kernel(
    float* __restrict__ buf, const float2* __restrict__ stats,
    const float* __restrict__ gamma, const float* __restrict__ beta, int p) {
  int t = blockIdx.x * 256 + threadIdx.x;   // grid exact: CHW
  int pp = p * p;
  int t2 = t / pp;
  int c = t2 % NCH;
  int n = t2 / NCH;
  float2 st = stats[n * 8 + (c >> 2)];
  float v = __fadd_rn(__fmul_rn(__fmul_rn(__fsub_rn(buf[t], st.x), st.y), gamma[c]), beta[c]);
  float tt = __fdiv_rn(v, 1.41421356237309504880f);  // f32(sqrt(2))
  float e = (float)erf((double)tt);
  buf[t] = __fmul_rn(__fmul_rn(0.5f, v), __fadd_rn(1.0f, e));
}

// ---------------------------------------------------------------------------
// Argmin with REFERENCE-EXACT f32 scores:
//   zz = pairwise32(z*z)  (numpy n=32 unrolled-8 tree)
//   m  = sequential f32 FMA chain over k (BLAS sgemm semantics)
//   d  = (zz + ee[v]) - 2f*m   (np expression order)
// strict < scan = np.argmin first-occurrence. Ties on the f32 grid resolve
// to the LOWER index, exactly like the reference.
// ---------------------------------------------------------------------------
__global__ __launch_bounds__(256) void argmin_kernel(
    const float* __restrict__ z, const float* __restrict__ emb,
    const float* __restrict__ ee, float* __restrict__ zq,
    float* __restrict__ idxout, double* __restrict__ part) {
  __shared__ double red[256];
  int r = blockIdx.x * 256 + threadIdx.x;   // grid exact: 576*256 rows
  const float* zr = z + (size_t)r * 32;

  float zv[32];
#pragma unroll
  for (int q = 0; q < 32; q++) zv[q] = zr[q];

  // zz: numpy pairwise over 32 squares
  float rr[8];
#pragma unroll
  for (int j = 0; j < 8; j++) rr[j] = __fmul_rn(zv[j], zv[j]);
#pragma unroll
  for (int i = 8; i < 32; i += 8)
#pragma unroll
    for (int j = 0; j < 8; j++) rr[j] = __fadd_rn(rr[j], __fmul_rn(zv[i + j], zv[i + j]));
  float zz = __fadd_rn(__fadd_rn(__fadd_rn(rr[0], rr[1]), __fadd_rn(rr[2], rr[3])),
                       __fadd_rn(__fadd_rn(rr[4], rr[5]), __fadd_rn(rr[6], rr[7])));

  float best = 3.402823466e+38f;
  int bi = 0;
  for (int v = 0; v < NV; v++) {
    const float* ep = emb + v * 32;         // wave-uniform -> scalar loads
    float m = 0.0f;
#pragma unroll
    for (int q = 0; q < 32; q++) m = fmaf(zv[q], ep[q], m);
    float d = __fsub_rn(__fadd_rn(zz, ee[v]), __fmul_rn(2.0f, m));
    if (d < best) { best = d; bi = v; }
  }

  double sse = 0.0;
#pragma unroll
  for (int q = 0; q < 32; q++) {
    float e = emb[bi * 32 + q];
    zq[(size_t)r * 32 + q] = e;
    double dd = (double)e - (double)zv[q];
    sse += dd * dd;
  }
  idxout[r] = (float)bi;

  red[threadIdx.x] = sse;
  __syncthreads();
  for (int st = 128; st > 0; st >>= 1) {
    if (threadIdx.x < st) red[threadIdx.x] += red[threadIdx.x + st];
    __syncthreads();
  }
  if (threadIdx.x == 0) part[blockIdx.x] = red[0];
}

__global__ __launch_bounds__(256) void sigmoid_kernel(
    const float* __restrict__ acc, float* __restrict__ out) {
  int t = blockIdx.x * 256 + threadIdx.x;
  out[t] = (float)(1.0 / (1.0 + exp(-(double)acc[t])));
}

__global__ void loss_kernel(const double* __restrict__ part, float* __restrict__ out) {
  double tot = 0.0;
  for (int s = 0; s < 4; s++) {
    double sse = 0.0;
    for (int b = 0; b < 576; b++) sse += part[s * 1024 + b];
    tot += 1.25 * sse / 4718592.0;
  }
  out[0] = (float)tot;
}

// ---------------------------------------------------------------------------
extern "C" void kernel_launch(void* const* d_in, const int* in_sizes, int n_in,
                              void* d_out, int out_size, void* d_ws, size_t ws_size,
                              hipStream_t stream) {
  const float* X   = (const float*)d_in[0];
  const float* EMB = (const float*)d_in[1];
  const float* PW1 = (const float*)d_in[2];
  const float* PB1 = (const float*)d_in[3];
  const float* PG  = (const float*)d_in[4];
  const float* PBT = (const float*)d_in[5];
  const float* PW2 = (const float*)d_in[6];
  const float* PB2 = (const float*)d_in[7];
  const float* RW1 = (const float*)d_in[8];
  const float* RB1 = (const float*)d_in[9];
  const float* RG  = (const float*)d_in[10];
  const float* RBT = (const float*)d_in[11];
  const float* RW2 = (const float*)d_in[12];
  const float* RB2 = (const float*)d_in[13];
  float* out = (float*)d_out;

  // workspace layout, total ~54.6 MiB:
  //   EE    @ 0         (8,192)       f32 |e|^2 (numpy pairwise)
  //   STATS @ 540672    (36,864)      float2 per-(n,g) mu/rs
  //   PART  @ 577536    (32,768)      f64 SSE partials
  //   P     @ 610304    (18,874,368)  f32 patch-major buffer
  //   H     @ 19484672  (18,874,368)  f32 patch-major buffer
  //   ACC   @ 38359040  (18,874,368)  f32 image-layout accumulator
  char* w = (char*)d_ws;
  float*  EE    = (float*)(w);
  float2* STATS = (float2*)(w + 540672UL);
  double* PART  = (double*)(w + 577536UL);
  float*  P     = (float*)(w + 610304UL);
  float*  H     = (float*)(w + 19484672UL);
  float*  ACC   = (float*)(w + 38359040UL);

  hipMemsetAsync(ACC, 0, 18874368UL, stream);
  prep_kernel<<<8, 256, 0, stream>>>(EMB, EE);

  const int PS[4] = {16, 32, 48, 64};
  for (int s = 0; s < 4; s++) {
    int p = PS[s], nw = 384 / p, N = nw * nw;
    int ngb = (N * 8) / 8;                   // gn_stats blocks (8 groups/block)

    unfold_kernel<<<18432, 256, 0, stream>>>(X, ACC, P, p, nw);
    // conv_block #1: P -> H, GN+GELU in H, H -> P (z)
    convp_kernel<0><<<18432, 256, 0, stream>>>(P, H, nullptr, nullptr,
                                               PW1 + s * 9216, PB1 + s * 32, p, nw);
    gn_stats_kernel<<<ngb, 64, 0, stream>>>(H, STATS, p);
    gn_gelu_kernel<<<18432, 256, 0, stream>>>(H, STATS, PG + s * 32, PBT + s * 32, p);
    convp_kernel<0><<<18432, 256, 0, stream>>>(H, P, nullptr, nullptr,
                                               PW2 + s * 9216, PB2 + s * 32, p, nw);
    // quantize: z (P) -> idx, zq into H, SSE partials
    argmin_kernel<<<576, 256, 0, stream>>>(P, EMB, EE, H,
                                           out + 4718592 + s * 147456, PART + s * 1024);
    // residual conv_block on zq: H -> P, GN+GELU in P, conv+fold into ACC
    convp_kernel<0><<<18432, 256, 0, stream>>>(H, P, nullptr, nullptr,
                                               RW1 + s * 9216, RB1 + s * 32, p, nw);
    gn_stats_kernel<<<ngb, 64, 0, stream>>>(P, STATS, p);
    gn_gelu_kernel<<<18432, 256, 0, stream>>>(P, STATS, RG + s * 32, RBT + s * 32, p);
    convp_kernel<1><<<18432, 256, 0, stream>>>(P, nullptr, H, ACC,
                                               RW2 + s * 9216, RB2 + s * 32, p, nw);
  }

  sigmoid_kernel<<<18432, 256, 0, stream>>>(ACC, out);
  loss_kernel<<<1, 1, 0, stream>>>(PART, out + 5308416);
}

// Round 6
// 4213.599 us; speedup vs baseline: 2.5434x; 2.5434x over previous
//
#include <hip/hip_runtime.h>
#include <cmath>

#define WIDTH 384
#define HW 147456        // 384*384
#define CHW 4718592      // 32*384*384
#define NCH 32
#define NV 2048

// ---------------------------------------------------------------------------
// numpy pairwise_sum replica, f32, contraction-proof.
// SQ=0: sum a[i]; SQ=1: sum (a[i]-mu)^2 (separate f32 sub, mul, add — like np).
// ---------------------------------------------------------------------------
template <int SQ>
__device__ float np_pw(const float* a, int n, float mu) {
  if (n < 8) {
    float res = 0.0f;
    for (int i = 0; i < n; i++) {
      float v = a[i];
      if (SQ) { float d = __fsub_rn(v, mu); v = __fmul_rn(d, d); }
      res = __fadd_rn(res, v);
    }
    return res;
  }
  if (n <= 128) {
    float r[8];
#pragma unroll
    for (int j = 0; j < 8; j++) {
      float v = a[j];
      if (SQ) { float d = __fsub_rn(v, mu); v = __fmul_rn(d, d); }
      r[j] = v;
    }
    int i;
    for (i = 8; i + 8 <= n; i += 8) {
#pragma unroll
      for (int j = 0; j < 8; j++) {
        float v = a[i + j];
        if (SQ) { float d = __fsub_rn(v, mu); v = __fmul_rn(d, d); }
        r[j] = __fadd_rn(r[j], v);
      }
    }
    float res = __fadd_rn(__fadd_rn(__fadd_rn(r[0], r[1]), __fadd_rn(r[2], r[3])),
                          __fadd_rn(__fadd_rn(r[4], r[5]), __fadd_rn(r[6], r[7])));
    for (; i < n; i++) {
      float v = a[i];
      if (SQ) { float d = __fsub_rn(v, mu); v = __fmul_rn(d, d); }
      res = __fadd_rn(res, v);
    }
    return res;
  }
  int n2 = n / 2; n2 -= n2 % 8;
  return __fadd_rn(np_pw<SQ>(a, n2, mu), np_pw<SQ>(a + n2, n - n2, mu));
}

// ---------------------------------------------------------------------------
// prep: ee[v] = numpy-pairwise |e|^2; WT = weights transposed to [layer][k][co]
// (k = ci*9 + dy*3 + dx) for wave-uniform contiguous scalar loads in conv.
// ---------------------------------------------------------------------------
__global__ __launch_bounds__(256) void prep_kernel(
    const float* __restrict__ pw1, const float* __restrict__ pw2,
    const float* __restrict__ rw1, const float* __restrict__ rw2,
    const float* __restrict__ emb, float* __restrict__ wt, float* __restrict__ ee) {
  int t = blockIdx.x * 256 + threadIdx.x;
  if (t < 147456) {
    int layer = t / 9216, r = t % 9216;
    int k = r / 32, co = r % 32;
    int set = layer >> 2, s = layer & 3;
    const float* src = set == 0 ? pw1 : set == 1 ? pw2 : set == 2 ? rw1 : rw2;
    wt[t] = src[s * 9216 + co * 288 + k];
  } else if (t < 147456 + NV) {
    int v = t - 147456;
    const float* e = emb + v * 32;
    float r[8];
#pragma unroll
    for (int j = 0; j < 8; j++) r[j] = __fmul_rn(e[j], e[j]);
#pragma unroll
    for (int i = 8; i < 32; i += 8)
#pragma unroll
      for (int j = 0; j < 8; j++) r[j] = __fadd_rn(r[j], __fmul_rn(e[i + j], e[i + j]));
    ee[v] = __fadd_rn(__fadd_rn(__fadd_rn(r[0], r[1]), __fadd_rn(r[2], r[3])),
                      __fadd_rn(__fadd_rn(r[4], r[5]), __fadd_rn(r[6], r[7])));
  }
}

// ---------------------------------------------------------------------------
// conv3x3, per-patch SAME zero pad. One thread = one pixel, ALL 32 co
// (32 independent FMA chains; weights via uniform scalar loads).
// Per-co chain order = (ci, dy, dx) ascending, identical to round-5 kernel;
// invalid taps contribute fmaf(0,w,a)=a exactly.
// MODE 0: patch-major in -> patch-major out
// MODE 1: residual in (x - acc, image layout, fuses unfold) -> patch-major out
// MODE 2: patch-major in; fold: acc_img += zq*0.5 + (conv+b)*0.5
// ---------------------------------------------------------------------------
template <int MODE>
__global__ __launch_bounds__(256) void conv32_kernel(
    const float* __restrict__ in, const float* __restrict__ x,
    const float* __restrict__ accin, float* __restrict__ outb,
    const float* __restrict__ zqb, float* __restrict__ acc,
    const float* __restrict__ wt, const float* __restrict__ bias, int p, int nw) {
  int t = blockIdx.x * 256 + threadIdx.x;   // grid exact: 576*256 = 147456 pixels
  int pp = p * p;
  int px = t % p; int t1 = t / p;
  int py = t1 % p;
  int n  = t1 / p;
  int i = n / nw, j = n % nw;

  // tap offsets + masks (ci-invariant)
  int off[9]; bool msk[9];
#pragma unroll
  for (int dy = 0; dy < 3; dy++) {
    int ly = py + dy - 1;
    bool vy = (unsigned)ly < (unsigned)p;
    int cy = vy ? ly : 0;
#pragma unroll
    for (int dx = 0; dx < 3; dx++) {
      int lx = px + dx - 1;
      bool vx = (unsigned)lx < (unsigned)p;
      int cx = vx ? lx : 0;
      msk[dy * 3 + dx] = vy && vx;
      if (MODE == 1) off[dy * 3 + dx] = (i * p + cy) * WIDTH + (j * p + cx);
      else           off[dy * 3 + dx] = cy * p + cx;
    }
  }

  const float* pin = (MODE == 1) ? nullptr : in + (size_t)n * NCH * pp;

  float a[NCH];
#pragma unroll
  for (int co = 0; co < NCH; co++) a[co] = 0.0f;

  for (int ci = 0; ci < NCH; ci++) {
    float tv[9];
#pragma unroll
    for (int k = 0; k < 9; k++) {
      float v;
      if (MODE == 1) {
        size_t ad = (size_t)ci * HW + off[k];
        v = __fsub_rn(x[ad], accin[ad]);
      } else {
        v = pin[(size_t)ci * pp + off[k]];
      }
      tv[k] = msk[k] ? v : 0.0f;
    }
    const float* wp = wt + ci * 288;        // [k][co], uniform -> s_load
#pragma unroll
    for (int k = 0; k < 9; k++) {
#pragma unroll
      for (int co = 0; co < NCH; co++)
        a[co] = fmaf(tv[k], wp[k * 32 + co], a[co]);
    }
  }

#pragma unroll
  for (int co = 0; co < NCH; co++) {
    float r = __fadd_rn(a[co], bias[co]);
    if (MODE == 2) {
      size_t img = (size_t)co * HW + (size_t)(i * p + py) * WIDTH + (j * p + px);
      size_t pt  = (size_t)n * NCH * pp + (size_t)co * pp + (size_t)py * p + px;
      float dec = __fadd_rn(__fmul_rn(zqb[pt], 0.5f), __fmul_rn(r, 0.5f));
      acc[img] = __fadd_rn(acc[img], dec);
    } else {
      outb[(size_t)n * NCH * pp + (size_t)co * pp + (size_t)py * p + px] = r;
    }
  }
}

// ---------------------------------------------------------------------------
// GroupNorm stats, numpy-exact (unchanged from passing round 5).
// ---------------------------------------------------------------------------
__global__ __launch_bounds__(64) void gn_stats_kernel(
    const float* __restrict__ buf, float2* __restrict__ stats, int p) {
  __shared__ float lds[8][8];
  __shared__ float mus[8];
  int gi = threadIdx.x >> 3, l = threadIdx.x & 7;
  int grp = blockIdx.x * 8 + gi;
  int pp = p * p, ne = 4 * pp, chunk = ne >> 3;
  const float* base = buf + ((size_t)(grp >> 3) * NCH + (size_t)(grp & 7) * 4) * pp;

  lds[gi][l] = np_pw<0>(base + l * chunk, chunk, 0.0f);
  __syncthreads();
  if (l == 0) {
    float* r = lds[gi];
    float s = __fadd_rn(__fadd_rn(__fadd_rn(r[0], r[1]), __fadd_rn(r[2], r[3])),
                        __fadd_rn(__fadd_rn(r[4], r[5]), __fadd_rn(r[6], r[7])));
    mus[gi] = __fdiv_rn(s, (float)ne);
  }
  __syncthreads();
  float mu = mus[gi];
  lds[gi][l] = np_pw<1>(base + l * chunk, chunk, mu);
  __syncthreads();
  if (l == 0) {
    float* r = lds[gi];
    float s2 = __fadd_rn(__fadd_rn(__fadd_rn(r[0], r[1]), __fadd_rn(r[2], r[3])),
                         __fadd_rn(__fadd_rn(r[4], r[5]), __fadd_rn(r[6], r[7])));
    float var = __fdiv_rn(s2, (float)ne);
    float rs = __fdiv_rn(1.0f, __fsqrt_rn(__fadd_rn(var, 1e-5f)));
    stats[grp] = make_float2(mu, rs);
  }
}

// ---------------------------------------------------------------------------
// GN affine + exact GELU (unchanged; erf = f64 erf rounded to f32).
// ---------------------------------------------------------------------------
__global__ __launch_bounds__(256) void gn_gelu_kernel(
    float* __restrict__ buf, const float2* __restrict__ stats,
    const float* __restrict__ gamma, const float* __restrict__ beta, int p) {
  int t = blockIdx.x * 256 + threadIdx.x;
  int pp = p * p;
  int t2 = t / pp;
  int c = t2 % NCH;
  int n = t2 / NCH;
  float2 st = stats[n * 8 + (c >> 2)];
  float v = __fadd_rn(__fmul_rn(__fmul_rn(__fsub_rn(buf[t], st.x), st.y), gamma[c]), beta[c]);
  float tt = __fdiv_rn(v, 1.41421356237309504880f);
  float e = (float)erf((double)tt);
  buf[t] = __fmul_rn(__fmul_rn(0.5f, v), __fadd_rn(1.0f, e));
}

// ---------------------------------------------------------------------------
// Argmin, reference-exact f32 scores, 4-way v-unroll (4 independent FMA
// chains for ILP; compares resolved in ascending v order -> first-occurrence
// semantics identical to np.argmin).
// ---------------------------------------------------------------------------
__global__ __launch_bounds__(256) void argmin_kernel(
    const float* __restrict__ z, const float* __restrict__ emb,
    const float* __restrict__ ee, float* __restrict__ zq,
    float* __restrict__ idxout, double* __restrict__ part) {
  __shared__ double red[256];
  int r = blockIdx.x * 256 + threadIdx.x;   // grid exact: 576*256 rows
  const float* zr = z + (size_t)r * 32;

  float zv[32];
#pragma unroll
  for (int q = 0; q < 32; q++) zv[q] = zr[q];

  // zz: numpy pairwise over 32 squares
  float rr[8];
#pragma unroll
  for (int j = 0; j < 8; j++) rr[j] = __fmul_rn(zv[j], zv[j]);
#pragma unroll
  for (int i = 8; i < 32; i += 8)
#pragma unroll
    for (int j = 0; j < 8; j++) rr[j] = __fadd_rn(rr[j], __fmul_rn(zv[i + j], zv[i + j]));
  float zz = __fadd_rn(__fadd_rn(__fadd_rn(rr[0], rr[1]), __fadd_rn(rr[2], rr[3])),
                       __fadd_rn(__fadd_rn(rr[4], rr[5]), __fadd_rn(rr[6], rr[7])));

  float best = 3.402823466e+38f;
  int bi = 0;
  for (int v = 0; v < NV; v += 4) {
    const float* e0 = emb + (size_t)v * 32;  // uniform -> scalar loads
    float m0 = 0.0f, m1 = 0.0f, m2 = 0.0f, m3 = 0.0f;
#pragma unroll
    for (int q = 0; q < 32; q++) {
      m0 = fmaf(zv[q], e0[q], m0);
      m1 = fmaf(zv[q], e0[32 + q], m1);
      m2 = fmaf(zv[q], e0[64 + q], m2);
      m3 = fmaf(zv[q], e0[96 + q], m3);
    }
    float d0 = __fsub_rn(__fadd_rn(zz, ee[v]),     __fmul_rn(2.0f, m0));
    float d1 = __fsub_rn(__fadd_rn(zz, ee[v + 1]), __fmul_rn(2.0f, m1));
    float d2 = __fsub_rn(__fadd_rn(zz, ee[v + 2]), __fmul_rn(2.0f, m2));
    float d3 = __fsub_rn(__fadd_rn(zz, ee[v + 3]), __fmul_rn(2.0f, m3));
    if (d0 < best) { best = d0; bi = v; }
    if (d1 < best) { best = d1; bi = v + 1; }
    if (d2 < best) { best = d2; bi = v + 2; }
    if (d3 < best) { best = d3; bi = v + 3; }
  }

  double sse = 0.0;
#pragma unroll
  for (int q = 0; q < 32; q++) {
    float e = emb[bi * 32 + q];
    zq[(size_t)r * 32 + q] = e;
    double dd = (double)e - (double)zv[q];
    sse += dd * dd;
  }
  idxout[r] = (float)bi;

  red[threadIdx.x] = sse;
  __syncthreads();
  for (int st = 128; st > 0; st >>= 1) {
    if (threadIdx.x < st) red[threadIdx.x] += red[threadIdx.x + st];
    __syncthreads();
  }
  if (threadIdx.x == 0) part[blockIdx.x] = red[0];
}

__global__ __launch_bounds__(256) void sigmoid_kernel(
    const float* __restrict__ acc, float* __restrict__ out) {
  int t = blockIdx.x * 256 + threadIdx.x;
  out[t] = (float)(1.0 / (1.0 + exp(-(double)acc[t])));
}

__global__ void loss_kernel(const double* __restrict__ part, float* __restrict__ out) {
  double tot = 0.0;
  for (int s = 0; s < 4; s++) {
    double sse = 0.0;
    for (int b = 0; b < 576; b++) sse += part[s * 1024 + b];
    tot += 1.25 * sse / 4718592.0;
  }
  out[0] = (float)tot;
}

// ---------------------------------------------------------------------------
extern "C" void kernel_launch(void* const* d_in, const int* in_sizes, int n_in,
                              void* d_out, int out_size, void* d_ws, size_t ws_size,
                              hipStream_t stream) {
  const float* X   = (const float*)d_in[0];
  const float* EMB = (const float*)d_in[1];
  const float* PW1 = (const float*)d_in[2];
  const float* PB1 = (const float*)d_in[3];
  const float* PG  = (const float*)d_in[4];
  const float* PBT = (const float*)d_in[5];
  const float* PW2 = (const float*)d_in[6];
  const float* PB2 = (const float*)d_in[7];
  const float* RW1 = (const float*)d_in[8];
  const float* RB1 = (const float*)d_in[9];
  const float* RG  = (const float*)d_in[10];
  const float* RBT = (const float*)d_in[11];
  const float* RW2 = (const float*)d_in[12];
  const float* RB2 = (const float*)d_in[13];
  float* out = (float*)d_out;

  // workspace layout (~55 MiB):
  //   EE    @ 0         (8,192)       f32 |e|^2
  //   WT    @ 8192      (589,824)     f32 transposed weights [16 layers][288][32]
  //   STATS @ 598016    (36,864)      float2 per-(n,g) mu/rs
  //   PART  @ 634880    (32,768)      f64 SSE partials
  //   P     @ 667648    (18,874,368)  f32 patch-major buffer
  //   H     @ 19542016  (18,874,368)  f32 patch-major buffer
  //   ACC   @ 38416384  (18,874,368)  f32 image-layout accumulator
  char* w = (char*)d_ws;
  float*  EE    = (float*)(w);
  float*  WT    = (float*)(w + 8192UL);
  float2* STATS = (float2*)(w + 598016UL);
  double* PART  = (double*)(w + 634880UL);
  float*  P     = (float*)(w + 667648UL);
  float*  H     = (float*)(w + 19542016UL);
  float*  ACC   = (float*)(w + 38416384UL);

  hipMemsetAsync(ACC, 0, 18874368UL, stream);
  prep_kernel<<<584, 256, 0, stream>>>(PW1, PW2, RW1, RW2, EMB, WT, EE);

  const int PS[4] = {16, 32, 48, 64};
  for (int s = 0; s < 4; s++) {
    int p = PS[s], nw = 384 / p, N = nw * nw;
    const float* wt_p1 = WT + (0 * 4 + s) * 9216;
    const float* wt_p2 = WT + (1 * 4 + s) * 9216;
    const float* wt_r1 = WT + (2 * 4 + s) * 9216;
    const float* wt_r2 = WT + (3 * 4 + s) * 9216;

    // conv_block #1 (fused unfold): (x - acc) -> H, GN+GELU in H, H -> P (z)
    conv32_kernel<1><<<576, 256, 0, stream>>>(nullptr, X, ACC, H, nullptr, nullptr,
                                              wt_p1, PB1 + s * 32, p, nw);
    gn_stats_kernel<<<N, 64, 0, stream>>>(H, STATS, p);
    gn_gelu_kernel<<<18432, 256, 0, stream>>>(H, STATS, PG + s * 32, PBT + s * 32, p);
    conv32_kernel<0><<<576, 256, 0, stream>>>(H, nullptr, nullptr, P, nullptr, nullptr,
                                              wt_p2, PB2 + s * 32, p, nw);
    // quantize: z (P) -> idx, zq into H, SSE partials
    argmin_kernel<<<576, 256, 0, stream>>>(P, EMB, EE, H,
                                           out + 4718592 + s * 147456, PART + s * 1024);
    // residual conv_block on zq: H -> P, GN+GELU in P, conv+fold into ACC
    conv32_kernel<0><<<576, 256, 0, stream>>>(H, nullptr, nullptr, P, nullptr, nullptr,
                                              wt_r1, RB1 + s * 32, p, nw);
    gn_stats_kernel<<<N, 64, 0, stream>>>(P, STATS, p);
    gn_gelu_kernel<<<18432, 256, 0, stream>>>(P, STATS, RG + s * 32, RBT + s * 32, p);
    conv32_kernel<2><<<576, 256, 0, stream>>>(P, nullptr, nullptr, nullptr, H, ACC,
                                              wt_r2, RB2 + s * 32, p, nw);
  }

  sigmoid_kernel<<<18432, 256, 0, stream>>>(ACC, out);
  loss_kernel<<<1, 1, 0, stream>>>(PART, out + 5308416);
}